// Round 4
// baseline (742.301 us; speedup 1.0000x reference)
//
#include <hip/hip_runtime.h>

#define N_GRID 144
#define INV_DX 128.0f
#define NBINS 4096           // 16 x 16 x 16 bins of 8^3 cells
#define SCAN_THREADS 1024
#define PER_THREAD 4         // 1024 * 4 = 4096
#define KP 8                 // particles per thread in hist/scatter

__device__ __forceinline__ int bin_of(float px, float py, float pz) {
    int bx = (int)(px * INV_DX);   // 0..127
    int by = (int)(py * INV_DX);
    int bz = (int)(pz * INV_DX);
    return ((bx >> 3) << 8) | ((by >> 3) << 4) | (bz >> 3);
}

__global__ void __launch_bounds__(256) hist_kernel(
    const float* __restrict__ pos, unsigned int* __restrict__ hist, int n)
{
    int base = blockIdx.x * (blockDim.x * KP) + threadIdx.x;
    float px[KP], py[KP], pz[KP];
    int ok[KP];
#pragma unroll
    for (int k = 0; k < KP; ++k) {
        int p = base + k * 256;
        ok[k] = (p < n);
        int q = ok[k] ? p : 0;
        px[k] = pos[3 * q + 0];
        py[k] = pos[3 * q + 1];
        pz[k] = pos[3 * q + 2];
    }
#pragma unroll
    for (int k = 0; k < KP; ++k) {
        if (ok[k]) atomicAdd(&hist[bin_of(px[k], py[k], pz[k])], 1u);
    }
}

__global__ void __launch_bounds__(SCAN_THREADS) scan_kernel(
    const unsigned int* __restrict__ hist, unsigned int* __restrict__ offs)
{
    __shared__ unsigned int partial[SCAN_THREADS];
    int t = threadIdx.x;
    unsigned int local[PER_THREAD];
    unsigned int s = 0;
    int base = t * PER_THREAD;
#pragma unroll
    for (int k = 0; k < PER_THREAD; ++k) {
        local[k] = s;
        s += hist[base + k];
    }
    partial[t] = s;
    __syncthreads();
    for (int d = 1; d < SCAN_THREADS; d <<= 1) {
        unsigned int v = (t >= d) ? partial[t - d] : 0u;
        __syncthreads();
        partial[t] += v;
        __syncthreads();
    }
    unsigned int chunk_excl = (t == 0) ? 0u : partial[t - 1];
#pragma unroll
    for (int k = 0; k < PER_THREAD; ++k)
        offs[base + k] = chunk_excl + local[k];
}

__global__ void __launch_bounds__(256) scatter_kernel(
    const float* __restrict__ pos, float4* __restrict__ sorted,
    unsigned int* __restrict__ offs, int n)
{
    int base = blockIdx.x * (blockDim.x * KP) + threadIdx.x;
    float px[KP], py[KP], pz[KP];
    int ok[KP], pidx[KP];
    unsigned int off[KP];
#pragma unroll
    for (int k = 0; k < KP; ++k) {
        int p = base + k * 256;
        ok[k] = (p < n);
        pidx[k] = p;
        int q = ok[k] ? p : 0;
        px[k] = pos[3 * q + 0];
        py[k] = pos[3 * q + 1];
        pz[k] = pos[3 * q + 2];
    }
#pragma unroll
    for (int k = 0; k < KP; ++k) {
        if (ok[k]) off[k] = atomicAdd(&offs[bin_of(px[k], py[k], pz[k])], 1u);
    }
#pragma unroll
    for (int k = 0; k < KP; ++k) {
        if (ok[k]) {
            float4 v;
            v.x = px[k]; v.y = py[k]; v.z = pz[k]; v.w = __int_as_float(pidx[k]);
            sorted[off[k]] = v;
        }
    }
}

__global__ void __launch_bounds__(256) gather_kernel(
    const float* __restrict__ grid,
    const float4* __restrict__ sorted,
    float* __restrict__ out, int n)
{
    int j = blockIdx.x * blockDim.x + threadIdx.x;
    if (j >= n) return;

    float4 p = sorted[j];
    int idx = __float_as_int(p.w);

    float nx = p.x * INV_DX;
    float ny = p.y * INV_DX;
    float nz = p.z * INV_DX;

    int bx = (int)nx;
    int by = (int)ny;
    int bz = (int)nz;

    float lx = nx - (float)bx;
    float ly = ny - (float)by;
    float lz = nz - (float)bz;

    float wx[3], wy[3], wz[3];
    wx[0] = 0.5f * (1.0f - lx) * (1.0f - lx);
    wx[1] = 0.75f - (0.5f - lx) * (0.5f - lx);
    wx[2] = 0.5f * lx * lx;
    wy[0] = 0.5f * (1.0f - ly) * (1.0f - ly);
    wy[1] = 0.75f - (0.5f - ly) * (0.5f - ly);
    wy[2] = 0.5f * ly * ly;
    wz[0] = 0.5f * (1.0f - lz) * (1.0f - lz);
    wz[1] = 0.75f - (0.5f - lz) * (0.5f - lz);
    wz[2] = 0.5f * lz * lz;

    const int s1 = N_GRID * 3;
    const int s0 = N_GRID * N_GRID * 3;
    const float* gbase = grid + (long)bx * s0 + by * s1 + bz * 3;

    float ox = 0.0f, oy = 0.0f, oz = 0.0f;

#pragma unroll
    for (int a = 0; a < 3; ++a) {
#pragma unroll
        for (int b = 0; b < 3; ++b) {
            const float* pp = gbase + a * s0 + b * s1;
            float wab = wx[a] * wy[b];
            float g0x = pp[0], g0y = pp[1], g0z = pp[2];
            float g1x = pp[3], g1y = pp[4], g1z = pp[5];
            float g2x = pp[6], g2y = pp[7], g2z = pp[8];
            float w0 = wab * wz[0];
            float w1 = wab * wz[1];
            float w2 = wab * wz[2];
            ox += w0 * g0x + w1 * g1x + w2 * g2x;
            oy += w0 * g0y + w1 * g1y + w2 * g2y;
            oz += w0 * g0z + w1 * g1z + w2 * g2z;
        }
    }

    out[3 * idx + 0] = ox;
    out[3 * idx + 1] = oy;
    out[3 * idx + 2] = oz;
}

// Fallback: naive per-particle gather in original order (used if ws too small)
__global__ void __launch_bounds__(256) g2p_naive_kernel(
    const float* __restrict__ grid, const float* __restrict__ pos,
    float* __restrict__ out, int n)
{
    int i = blockIdx.x * blockDim.x + threadIdx.x;
    if (i >= n) return;
    float px = pos[3 * i + 0], py = pos[3 * i + 1], pz = pos[3 * i + 2];
    float nx = px * INV_DX, ny = py * INV_DX, nz = pz * INV_DX;
    int bx = (int)nx, by = (int)ny, bz = (int)nz;
    float lx = nx - bx, ly = ny - by, lz = nz - bz;
    float wx[3], wy[3], wz[3];
    wx[0] = 0.5f * (1.0f - lx) * (1.0f - lx);
    wx[1] = 0.75f - (0.5f - lx) * (0.5f - lx);
    wx[2] = 0.5f * lx * lx;
    wy[0] = 0.5f * (1.0f - ly) * (1.0f - ly);
    wy[1] = 0.75f - (0.5f - ly) * (0.5f - ly);
    wy[2] = 0.5f * ly * ly;
    wz[0] = 0.5f * (1.0f - lz) * (1.0f - lz);
    wz[1] = 0.75f - (0.5f - lz) * (0.5f - lz);
    wz[2] = 0.5f * lz * lz;
    const int s1 = N_GRID * 3, s0 = N_GRID * N_GRID * 3;
    const float* gbase = grid + (long)bx * s0 + by * s1 + bz * 3;
    float ox = 0, oy = 0, oz = 0;
#pragma unroll
    for (int a = 0; a < 3; ++a)
#pragma unroll
        for (int b = 0; b < 3; ++b) {
            const float* pp = gbase + a * s0 + b * s1;
            float wab = wx[a] * wy[b];
            float w0 = wab * wz[0], w1 = wab * wz[1], w2 = wab * wz[2];
            ox += w0 * pp[0] + w1 * pp[3] + w2 * pp[6];
            oy += w0 * pp[1] + w1 * pp[4] + w2 * pp[7];
            oz += w0 * pp[2] + w1 * pp[5] + w2 * pp[8];
        }
    out[3 * i + 0] = ox;
    out[3 * i + 1] = oy;
    out[3 * i + 2] = oz;
}

extern "C" void kernel_launch(void* const* d_in, const int* in_sizes, int n_in,
                              void* d_out, int out_size, void* d_ws, size_t ws_size,
                              hipStream_t stream) {
    const float* grid = (const float*)d_in[0];
    const float* pos  = (const float*)d_in[1];
    float* out        = (float*)d_out;
    int n = in_sizes[1] / 3;

    int block = 256;
    int blocks = (n + block - 1) / block;
    int blocksK = (n + block * KP - 1) / (block * KP);

    size_t need = (1u << 20) + (size_t)n * sizeof(float4);
    if (ws_size < need) {
        g2p_naive_kernel<<<blocks, block, 0, stream>>>(grid, pos, out, n);
        return;
    }

    unsigned int* hist = (unsigned int*)d_ws;
    unsigned int* offs = hist + NBINS;
    float4* sorted = (float4*)((char*)d_ws + (1u << 20));

    hipMemsetAsync(hist, 0, NBINS * sizeof(unsigned int), stream);
    hist_kernel<<<blocksK, block, 0, stream>>>(pos, hist, n);
    scan_kernel<<<1, SCAN_THREADS, 0, stream>>>(hist, offs);
    scatter_kernel<<<blocksK, block, 0, stream>>>(pos, sorted, offs, n);
    gather_kernel<<<blocks, block, 0, stream>>>(grid, sorted, out, n);
}

// Round 5
// 464.510 us; speedup vs baseline: 1.5980x; 1.5980x over previous
//
#include <hip/hip_runtime.h>

#define N_GRID 144
#define INV_DX 128.0f
#define NBINS 32768          // 32 x 32 x 32 bins of 4^3 cells
#define SCAN_THREADS 1024
#define PER_THREAD 32        // 1024 * 32 = 32768
#define KP 8                 // particles per thread in hist/scatter

__device__ __forceinline__ int bin_of(float px, float py, float pz) {
    int bx = (int)(px * INV_DX);   // 0..127
    int by = (int)(py * INV_DX);
    int bz = (int)(pz * INV_DX);
    return ((bx >> 2) << 10) | ((by >> 2) << 5) | (bz >> 2);
}

__global__ void __launch_bounds__(256) hist_kernel(
    const float* __restrict__ pos, unsigned int* __restrict__ hist, int n)
{
    int base = blockIdx.x * (blockDim.x * KP) + threadIdx.x;
    float px[KP], py[KP], pz[KP];
    int ok[KP];
#pragma unroll
    for (int k = 0; k < KP; ++k) {
        int p = base + k * 256;
        ok[k] = (p < n);
        int q = ok[k] ? p : 0;
        px[k] = pos[3 * q + 0];
        py[k] = pos[3 * q + 1];
        pz[k] = pos[3 * q + 2];
    }
#pragma unroll
    for (int k = 0; k < KP; ++k) {
        if (ok[k]) atomicAdd(&hist[bin_of(px[k], py[k], pz[k])], 1u);
    }
}

__global__ void __launch_bounds__(SCAN_THREADS) scan_kernel(
    const unsigned int* __restrict__ hist, unsigned int* __restrict__ offs)
{
    __shared__ unsigned int partial[SCAN_THREADS];
    int t = threadIdx.x;
    unsigned int local[PER_THREAD];
    unsigned int s = 0;
    int base = t * PER_THREAD;
#pragma unroll
    for (int k = 0; k < PER_THREAD; ++k) {
        local[k] = s;
        s += hist[base + k];
    }
    partial[t] = s;
    __syncthreads();
    for (int d = 1; d < SCAN_THREADS; d <<= 1) {
        unsigned int v = (t >= d) ? partial[t - d] : 0u;
        __syncthreads();
        partial[t] += v;
        __syncthreads();
    }
    unsigned int chunk_excl = (t == 0) ? 0u : partial[t - 1];
#pragma unroll
    for (int k = 0; k < PER_THREAD; ++k)
        offs[base + k] = chunk_excl + local[k];
}

// XCD-filtered scatter: 8 blocks per particle chunk; block (chunk, owner) only
// scatters particles whose bin's x-octant == owner. With round-robin
// blockIdx->XCD dispatch, all writers of a given `sorted` cache line are on
// the same XCD, so partial-line stores merge in that XCD's L2.
// Correct regardless of actual block->XCD mapping (filter is exact).
__global__ void __launch_bounds__(256) scatter_kernel(
    const float* __restrict__ pos, float4* __restrict__ sorted,
    unsigned int* __restrict__ offs, int n)
{
    int owner = blockIdx.x & 7;
    int chunk = blockIdx.x >> 3;
    int base = chunk * (256 * KP) + threadIdx.x;
    float px[KP], py[KP], pz[KP];
    int ok[KP], pidx[KP], bn[KP];
    unsigned int off[KP];
#pragma unroll
    for (int k = 0; k < KP; ++k) {
        int p = base + k * 256;
        ok[k] = (p < n);
        pidx[k] = p;
        int q = ok[k] ? p : 0;
        px[k] = pos[3 * q + 0];
        py[k] = pos[3 * q + 1];
        pz[k] = pos[3 * q + 2];
    }
#pragma unroll
    for (int k = 0; k < KP; ++k) {
        bn[k] = bin_of(px[k], py[k], pz[k]);
        ok[k] = ok[k] && ((bn[k] >> 12) == owner);   // x-octant filter
    }
#pragma unroll
    for (int k = 0; k < KP; ++k) {
        if (ok[k]) off[k] = atomicAdd(&offs[bn[k]], 1u);
    }
#pragma unroll
    for (int k = 0; k < KP; ++k) {
        if (ok[k]) {
            float4 v;
            v.x = px[k]; v.y = py[k]; v.z = pz[k]; v.w = __int_as_float(pidx[k]);
            sorted[off[k]] = v;
        }
    }
}

__global__ void __launch_bounds__(256) gather_kernel(
    const float* __restrict__ grid,
    const float4* __restrict__ sorted,
    float* __restrict__ out, int n)
{
    int j = blockIdx.x * blockDim.x + threadIdx.x;
    if (j >= n) return;

    float4 p = sorted[j];
    int idx = __float_as_int(p.w);

    float nx = p.x * INV_DX;
    float ny = p.y * INV_DX;
    float nz = p.z * INV_DX;

    int bx = (int)nx;
    int by = (int)ny;
    int bz = (int)nz;

    float lx = nx - (float)bx;
    float ly = ny - (float)by;
    float lz = nz - (float)bz;

    float wx[3], wy[3], wz[3];
    wx[0] = 0.5f * (1.0f - lx) * (1.0f - lx);
    wx[1] = 0.75f - (0.5f - lx) * (0.5f - lx);
    wx[2] = 0.5f * lx * lx;
    wy[0] = 0.5f * (1.0f - ly) * (1.0f - ly);
    wy[1] = 0.75f - (0.5f - ly) * (0.5f - ly);
    wy[2] = 0.5f * ly * ly;
    wz[0] = 0.5f * (1.0f - lz) * (1.0f - lz);
    wz[1] = 0.75f - (0.5f - lz) * (0.5f - lz);
    wz[2] = 0.5f * lz * lz;

    const int s1 = N_GRID * 3;
    const int s0 = N_GRID * N_GRID * 3;
    const float* gbase = grid + (long)bx * s0 + by * s1 + bz * 3;

    float ox = 0.0f, oy = 0.0f, oz = 0.0f;

#pragma unroll
    for (int a = 0; a < 3; ++a) {
#pragma unroll
        for (int b = 0; b < 3; ++b) {
            const float* pp = gbase + a * s0 + b * s1;
            float wab = wx[a] * wy[b];
            float g0x = pp[0], g0y = pp[1], g0z = pp[2];
            float g1x = pp[3], g1y = pp[4], g1z = pp[5];
            float g2x = pp[6], g2y = pp[7], g2z = pp[8];
            float w0 = wab * wz[0];
            float w1 = wab * wz[1];
            float w2 = wab * wz[2];
            ox += w0 * g0x + w1 * g1x + w2 * g2x;
            oy += w0 * g0y + w1 * g1y + w2 * g2y;
            oz += w0 * g0z + w1 * g1z + w2 * g2z;
        }
    }

    out[3 * idx + 0] = ox;
    out[3 * idx + 1] = oy;
    out[3 * idx + 2] = oz;
}

// Fallback: naive per-particle gather in original order (used if ws too small)
__global__ void __launch_bounds__(256) g2p_naive_kernel(
    const float* __restrict__ grid, const float* __restrict__ pos,
    float* __restrict__ out, int n)
{
    int i = blockIdx.x * blockDim.x + threadIdx.x;
    if (i >= n) return;
    float px = pos[3 * i + 0], py = pos[3 * i + 1], pz = pos[3 * i + 2];
    float nx = px * INV_DX, ny = py * INV_DX, nz = pz * INV_DX;
    int bx = (int)nx, by = (int)ny, bz = (int)nz;
    float lx = nx - bx, ly = ny - by, lz = nz - bz;
    float wx[3], wy[3], wz[3];
    wx[0] = 0.5f * (1.0f - lx) * (1.0f - lx);
    wx[1] = 0.75f - (0.5f - lx) * (0.5f - lx);
    wx[2] = 0.5f * lx * lx;
    wy[0] = 0.5f * (1.0f - ly) * (1.0f - ly);
    wy[1] = 0.75f - (0.5f - ly) * (0.5f - ly);
    wy[2] = 0.5f * ly * ly;
    wz[0] = 0.5f * (1.0f - lz) * (1.0f - lz);
    wz[1] = 0.75f - (0.5f - lz) * (0.5f - lz);
    wz[2] = 0.5f * lz * lz;
    const int s1 = N_GRID * 3, s0 = N_GRID * N_GRID * 3;
    const float* gbase = grid + (long)bx * s0 + by * s1 + bz * 3;
    float ox = 0, oy = 0, oz = 0;
#pragma unroll
    for (int a = 0; a < 3; ++a)
#pragma unroll
        for (int b = 0; b < 3; ++b) {
            const float* pp = gbase + a * s0 + b * s1;
            float wab = wx[a] * wy[b];
            float w0 = wab * wz[0], w1 = wab * wz[1], w2 = wab * wz[2];
            ox += w0 * pp[0] + w1 * pp[3] + w2 * pp[6];
            oy += w0 * pp[1] + w1 * pp[4] + w2 * pp[7];
            oz += w0 * pp[2] + w1 * pp[5] + w2 * pp[8];
        }
    out[3 * i + 0] = ox;
    out[3 * i + 1] = oy;
    out[3 * i + 2] = oz;
}

extern "C" void kernel_launch(void* const* d_in, const int* in_sizes, int n_in,
                              void* d_out, int out_size, void* d_ws, size_t ws_size,
                              hipStream_t stream) {
    const float* grid = (const float*)d_in[0];
    const float* pos  = (const float*)d_in[1];
    float* out        = (float*)d_out;
    int n = in_sizes[1] / 3;

    int block = 256;
    int blocks = (n + block - 1) / block;
    int blocksK = (n + block * KP - 1) / (block * KP);

    size_t need = (1u << 20) + (size_t)n * sizeof(float4);
    if (ws_size < need) {
        g2p_naive_kernel<<<blocks, block, 0, stream>>>(grid, pos, out, n);
        return;
    }

    unsigned int* hist = (unsigned int*)d_ws;
    unsigned int* offs = hist + NBINS;
    float4* sorted = (float4*)((char*)d_ws + (1u << 20));

    hipMemsetAsync(hist, 0, NBINS * sizeof(unsigned int), stream);
    hist_kernel<<<blocksK, block, 0, stream>>>(pos, hist, n);
    scan_kernel<<<1, SCAN_THREADS, 0, stream>>>(hist, offs);
    scatter_kernel<<<blocksK * 8, block, 0, stream>>>(pos, sorted, offs, n);
    gather_kernel<<<blocks, block, 0, stream>>>(grid, sorted, out, n);
}